// Round 9
// baseline (57.929 us; speedup 1.0000x reference)
//
#include <hip/hip_runtime.h>
#include <math.h>

#define Bsz 8
#define NP 9
#define OC 8
#define TILE 256           // pixels per block (2 image rows)
#define BPB 64             // blocks per batch
#define THREADS 256
#define NR 72              // (cls,pt) pairs
#define FLAG_MAGIC 0x1357BDFu

// Single fused kernel.
// Phase A: argmax class straight from global + ballot-compacted class lists.
// Phase B: 216 threads (8 cls x 9 pts x 3 slices) walk their class list,
//          recompute softplus/R/q from staged dir/w, accumulate in registers.
// Phase C: write transposed partial, release-store per-block flag; the
//          blockIdx.x==63 block of each batch acquire-spins on its batch's 64
//          flags, then wave-per-row f64 butterfly + 2x2 solve -> out.
__global__ __launch_bounds__(THREADS) void cls_vote_fused(
    const float* __restrict__ seg, const float* __restrict__ direct,
    const float* __restrict__ wts, float* __restrict__ partial,
    unsigned* __restrict__ flags, float* __restrict__ out)
{
    __shared__ float ls_dir[TILE * 18];         // 18432 B
    __shared__ float ls_w[TILE * 9];            //  9216 B
    __shared__ unsigned char ls_list[OC * TILE];//  2048 B
    __shared__ int ls_cnt[4][OC];               //   128 B
    __shared__ int ls_off[4][OC];               //   128 B
    __shared__ int ls_total[OC];                //    32 B
    __shared__ float ls_merge[216][5];          //  4320 B  (~34.3 KB -> 4 blk/CU)

    const int b = blockIdx.y;
    const int tid = threadIdx.x;
    const int lane = tid & 63;
    const int w = tid >> 6;
    const long gbase = (long)b * 16384 + blockIdx.x * TILE;

    // ---- coalesced float4 staging of dir/w ----
    {
        const float4* gd = (const float4*)(direct + gbase * 18); // 1152 float4
        const float4* gw = (const float4*)(wts + gbase * 9);     // 576 float4
        float4* d4 = (float4*)ls_dir;
        float4* w4 = (float4*)ls_w;
#pragma unroll
        for (int k = 0; k < 4; ++k) d4[tid + k * THREADS] = gd[tid + k * THREADS];
        if (tid < 128) d4[tid + 1024] = gd[tid + 1024];
#pragma unroll
        for (int k = 0; k < 2; ++k) w4[tid + k * THREADS] = gw[tid + k * THREADS];
        if (tid < 64) w4[tid + 512] = gw[tid + 512];
    }

    // ---- Phase A: argmax from global + ballot compaction ----
    int cls;
    int mypos = 0;
    {
        const float* s = seg + (gbase + tid) * 9;
        float m = s[0];
        int am = 0;
#pragma unroll
        for (int c = 1; c < 9; ++c) {
            float v = s[c];
            if (v > m) { m = v; am = c; }
        }
        cls = am - 1;  // -1 = background

        const unsigned long long lt = (1ull << lane) - 1ull;
#pragma unroll
        for (int c = 0; c < OC; ++c) {
            unsigned long long mask = __ballot(cls == c);
            if (lane == 0) ls_cnt[w][c] = __popcll(mask);
            if (cls == c) mypos = __popcll(mask & lt);
        }
    }
    __syncthreads();

    if (tid < OC) {  // cross-wave exclusive prefix per class
        int base = 0;
#pragma unroll
        for (int ww = 0; ww < 4; ++ww) {
            ls_off[ww][tid] = base;
            base += ls_cnt[ww][tid];
        }
        ls_total[tid] = base;
    }
    __syncthreads();

    if (cls >= 0)
        ls_list[cls * TILE + ls_off[w][cls] + mypos] = (unsigned char)tid;
    __syncthreads();

    // ---- Phase B: gather over compacted lists, accumulate in registers ----
    if (tid < 216) {
        const int s  = tid % 3;
        const int pp = (tid / 3) % 9;
        const int cl = tid / 27;
        const int n = ls_total[cl];
        const unsigned char* list = ls_list + cl * TILE;
        const float rowbase = (float)(blockIdx.x * 2) + 0.5f;

        float a0 = 0.f, a1 = 0.f, a2 = 0.f, a3 = 0.f, a4 = 0.f;
        for (int k = s; k < n; k += 3) {
            const int pix = list[k];
            const float2 nd = *(const float2*)(ls_dir + pix * 18 + pp * 2);
            const float wx = ls_w[pix * 9 + pp];
            float e = __expf(wx);
            float sp = (wx > 15.f) ? wx : __logf(1.f + e);
            float nx = nd.x, ny = nd.y;
            float nn = nx * nx + ny * ny;
            float R00, R01, R11;
            if (nn > 0.f) {
                float inv = __builtin_amdgcn_rcpf(nn);
                R00 = sp * (1.f - nx * nx * inv);
                R01 = -sp * (nx * ny * inv);
                R11 = sp * (1.f - ny * ny * inv);
            } else {  // divide_no_nan: n == 0 -> R = w * I
                R00 = sp; R01 = 0.f; R11 = sp;
            }
            float ch = (rowbase + (float)(pix >> 7)) * 0.0078125f;
            float cw = ((float)(pix & 127) + 0.5f) * 0.0078125f;
            a0 += R00;
            a1 += R01;
            a2 += R11;
            a3 += R00 * ch + R01 * cw;
            a4 += R01 * ch + R11 * cw;
        }
        ls_merge[tid][0] = a0;
        ls_merge[tid][1] = a1;
        ls_merge[tid][2] = a2;
        ls_merge[tid][3] = a3;
        ls_merge[tid][4] = a4;
    }
    __syncthreads();

    // ---- merge 3 slices, write transposed block partial ----
    if (tid < NR) {
        float* outp = partial + ((long)(b * NR + tid) * BPB + blockIdx.x) * 5;
#pragma unroll
        for (int f = 0; f < 5; ++f)
            outp[f] = ls_merge[tid * 3 + 0][f] + ls_merge[tid * 3 + 1][f] +
                      ls_merge[tid * 3 + 2][f];
    }
    __syncthreads();

    // ---- Phase C: publish flag; batch-reducer block does the solve ----
    if (tid == 0) {
        __threadfence();  // make this block's partial visible device-wide
        __hip_atomic_store(&flags[b * BPB + blockIdx.x], FLAG_MAGIC,
                           __ATOMIC_RELEASE, __HIP_MEMORY_SCOPE_AGENT);
    }
    if (blockIdx.x != BPB - 1) return;

    // reducer: wait for all 64 flags of this batch (acquire = L2 invalidate)
    if (tid < BPB) {
        while (__hip_atomic_load(&flags[b * BPB + tid], __ATOMIC_ACQUIRE,
                                 __HIP_MEMORY_SCOPE_AGENT) != FLAG_MAGIC) {
            __builtin_amdgcn_s_sleep(1);
        }
    }
    __syncthreads();

    // wave-per-row: 64 lanes read 64 consecutive 20-B records, f64 butterfly
    for (int r = w; r < NR; r += 4) {
        const float* pp = partial + ((long)(b * NR + r) * BPB + lane) * 5;
        double a  = (double)pp[0];
        double bb = (double)pp[1];
        double c  = (double)pp[2];
        double q0 = (double)pp[3];
        double q1 = (double)pp[4];

#pragma unroll
        for (int off = 1; off < 64; off <<= 1) {
            a  += __shfl_xor(a, off, 64);
            bb += __shfl_xor(bb, off, 64);
            c  += __shfl_xor(c, off, 64);
            q0 += __shfl_xor(q0, off, 64);
            q1 += __shfl_xor(q1, off, 64);
        }

        if (lane == 0) {
            double det = a * c - bb * bb;
            double p0 = 0.0, p1 = 0.0;
            if (det != 0.0) {
                double ia = c / det, ib = -bb / det, ic = a / det;
                p0 = ia * q0 + ib * q1;
                p1 = ib * q0 + ic * q1;
            }
            const int id = b * NR + r;
            out[2 * id + 0] = (float)(p0 * 128.0);
            out[2 * id + 1] = (float)(p1 * 128.0);
        }
    }
}

extern "C" void kernel_launch(void* const* d_in, const int* in_sizes, int n_in,
                              void* d_out, int out_size, void* d_ws, size_t ws_size,
                              hipStream_t stream) {
    const float* seg    = (const float*)d_in[0];
    const float* direct = (const float*)d_in[1];
    const float* wts    = (const float*)d_in[2];
    float* out = (float*)d_out;
    float* partial = (float*)d_ws;                              // 737,280 B
    unsigned* flags = (unsigned*)((char*)d_ws + 737280);        // 2,048 B

    dim3 grid(BPB, Bsz);
    cls_vote_fused<<<grid, THREADS, 0, stream>>>(seg, direct, wts, partial,
                                                 flags, out);
}

// Round 10
// 14.355 us; speedup vs baseline: 4.0353x; 4.0353x over previous
//
#include <hip/hip_runtime.h>
#include <math.h>

#define Bsz 8
#define NP 9
#define OC 8
#define TILE 256           // pixels per block (2 image rows)
#define BPB 64             // blocks per batch
#define THREADS 256
#define NR 72              // (cls,pt) pairs

// Kernel 1: per-block class-gather reduction, zero atomics.
// Phase A: seg staged via float4 -> LDS (TA-friendly), argmax from LDS
//          (stride 9, coprime 32 -> 2 lanes/bank, free), ballot compaction.
// Phase B: 216 threads = (8 cls x 9 pts x 3 slices) walk their class list,
//          recompute softplus/R/q from staged dir/w, accumulate in registers.
//          ls_merge ALIASES ls_seg (dead after phase A) -> 39.2 KB, 4 blk/CU.
// Partial layout transposed for k2 coalescing: [(b*72 + r)*64 + blk]*5 + f.
__global__ __launch_bounds__(THREADS) void cls_vote_partial(
    const float* __restrict__ seg, const float* __restrict__ direct,
    const float* __restrict__ wts, float* __restrict__ partial)
{
    __shared__ float ls_dir[TILE * 18];         // 18432 B
    __shared__ float ls_w[TILE * 9];            //  9216 B
    __shared__ float ls_seg[TILE * 9];          //  9216 B (reused as merge)
    __shared__ unsigned char ls_list[OC * TILE];//  2048 B
    __shared__ int ls_cnt[4][OC];               //   128 B
    __shared__ int ls_off[4][OC];               //   128 B
    __shared__ int ls_total[OC];                //    32 B  (~39.2 KB -> 4 blk/CU)
    float (*ls_merge)[5] = (float(*)[5])ls_seg; // alias: seg dead after phase A

    const int b = blockIdx.y;
    const int tid = threadIdx.x;
    const int lane = tid & 63;
    const int w = tid >> 6;
    const long gbase = (long)b * 16384 + blockIdx.x * TILE;

    // ---- coalesced float4 staging of seg/dir/w ----
    {
        const float4* gs = (const float4*)(seg + gbase * 9);     // 576 float4
        const float4* gd = (const float4*)(direct + gbase * 18); // 1152 float4
        const float4* gw = (const float4*)(wts + gbase * 9);     // 576 float4
        float4* s4 = (float4*)ls_seg;
        float4* d4 = (float4*)ls_dir;
        float4* w4 = (float4*)ls_w;
#pragma unroll
        for (int k = 0; k < 2; ++k) s4[tid + k * THREADS] = gs[tid + k * THREADS];
        if (tid < 64) s4[tid + 512] = gs[tid + 512];
#pragma unroll
        for (int k = 0; k < 4; ++k) d4[tid + k * THREADS] = gd[tid + k * THREADS];
        if (tid < 128) d4[tid + 1024] = gd[tid + 1024];
#pragma unroll
        for (int k = 0; k < 2; ++k) w4[tid + k * THREADS] = gw[tid + k * THREADS];
        if (tid < 64) w4[tid + 512] = gw[tid + 512];
    }
    __syncthreads();

    // ---- Phase A: argmax from LDS + ballot compaction ----
    int cls;
    int mypos = 0;
    {
        const float* s = ls_seg + tid * 9;
        float m = s[0];
        int am = 0;
#pragma unroll
        for (int c = 1; c < 9; ++c) {
            float v = s[c];
            if (v > m) { m = v; am = c; }
        }
        cls = am - 1;  // -1 = background

        const unsigned long long lt = (1ull << lane) - 1ull;
#pragma unroll
        for (int c = 0; c < OC; ++c) {
            unsigned long long mask = __ballot(cls == c);
            if (lane == 0) ls_cnt[w][c] = __popcll(mask);
            if (cls == c) mypos = __popcll(mask & lt);
        }
    }
    __syncthreads();

    if (tid < OC) {  // cross-wave exclusive prefix per class
        int base = 0;
#pragma unroll
        for (int ww = 0; ww < 4; ++ww) {
            ls_off[ww][tid] = base;
            base += ls_cnt[ww][tid];
        }
        ls_total[tid] = base;
    }
    __syncthreads();

    if (cls >= 0)
        ls_list[cls * TILE + ls_off[w][cls] + mypos] = (unsigned char)tid;
    __syncthreads();

    // ---- Phase B: gather over compacted lists, accumulate in registers ----
    if (tid < 216) {
        const int s  = tid % 3;
        const int pp = (tid / 3) % 9;
        const int cl = tid / 27;
        const int n = ls_total[cl];
        const unsigned char* list = ls_list + cl * TILE;
        const float rowbase = (float)(blockIdx.x * 2) + 0.5f;

        float a0 = 0.f, a1 = 0.f, a2 = 0.f, a3 = 0.f, a4 = 0.f;
        for (int k = s; k < n; k += 3) {
            const int pix = list[k];
            const float2 nd = *(const float2*)(ls_dir + pix * 18 + pp * 2);
            const float wx = ls_w[pix * 9 + pp];
            float e = __expf(wx);
            float sp = (wx > 15.f) ? wx : __logf(1.f + e);
            float nx = nd.x, ny = nd.y;
            float nn = nx * nx + ny * ny;
            float R00, R01, R11;
            if (nn > 0.f) {
                float inv = __builtin_amdgcn_rcpf(nn);
                R00 = sp * (1.f - nx * nx * inv);
                R01 = -sp * (nx * ny * inv);
                R11 = sp * (1.f - ny * ny * inv);
            } else {  // divide_no_nan: n == 0 -> R = w * I
                R00 = sp; R01 = 0.f; R11 = sp;
            }
            float ch = (rowbase + (float)(pix >> 7)) * 0.0078125f;
            float cw = ((float)(pix & 127) + 0.5f) * 0.0078125f;
            a0 += R00;
            a1 += R01;
            a2 += R11;
            a3 += R00 * ch + R01 * cw;
            a4 += R01 * ch + R11 * cw;
        }
        ls_merge[tid][0] = a0;
        ls_merge[tid][1] = a1;
        ls_merge[tid][2] = a2;
        ls_merge[tid][3] = a3;
        ls_merge[tid][4] = a4;
    }
    __syncthreads();

    // ---- merge 3 slices, write transposed block partial ----
    if (tid < NR) {
        float* outp = partial + ((long)(b * NR + tid) * BPB + blockIdx.x) * 5;
#pragma unroll
        for (int f = 0; f < 5; ++f)
            outp[f] = ls_merge[tid * 3 + 0][f] + ls_merge[tid * 3 + 1][f] +
                      ls_merge[tid * 3 + 2][f];
    }
}

// Kernel 2: one wave per (b,cls,pt). 64 lanes read 64 consecutive 20-B
// records (coalesced 1280 B), f64 butterfly reduce, lane 0 solves 2x2.
__global__ __launch_bounds__(256) void cls_vote_solve(
    const float* __restrict__ partial, float* __restrict__ out)
{
    const int wave = threadIdx.x >> 6;
    const int lane = threadIdx.x & 63;
    const int id = blockIdx.x * 4 + wave;   // (b*72 + r), r = cls*9+pt
    if (id >= Bsz * NR) return;

    const float* pp = partial + ((long)id * BPB + lane) * 5;
    double a  = (double)pp[0];
    double bb = (double)pp[1];
    double c  = (double)pp[2];
    double q0 = (double)pp[3];
    double q1 = (double)pp[4];

#pragma unroll
    for (int off = 1; off < 64; off <<= 1) {
        a  += __shfl_xor(a, off, 64);
        bb += __shfl_xor(bb, off, 64);
        c  += __shfl_xor(c, off, 64);
        q0 += __shfl_xor(q0, off, 64);
        q1 += __shfl_xor(q1, off, 64);
    }

    if (lane == 0) {
        double det = a * c - bb * bb;
        double p0 = 0.0, p1 = 0.0;
        if (det != 0.0) {
            double ia = c / det, ib = -bb / det, ic = a / det;
            p0 = ia * q0 + ib * q1;
            p1 = ib * q0 + ic * q1;
        }
        out[2 * id + 0] = (float)(p0 * 128.0);
        out[2 * id + 1] = (float)(p1 * 128.0);
    }
}

extern "C" void kernel_launch(void* const* d_in, const int* in_sizes, int n_in,
                              void* d_out, int out_size, void* d_ws, size_t ws_size,
                              hipStream_t stream) {
    const float* seg    = (const float*)d_in[0];
    const float* direct = (const float*)d_in[1];
    const float* wts    = (const float*)d_in[2];
    float* out = (float*)d_out;
    float* partial = (float*)d_ws;  // 8*72*64*5*4 = 737,280 B

    dim3 grid1(BPB, Bsz);
    cls_vote_partial<<<grid1, THREADS, 0, stream>>>(seg, direct, wts, partial);

    int nwaves = Bsz * NR;          // 576 waves, 4 per block
    cls_vote_solve<<<nwaves / 4, 256, 0, stream>>>(partial, out);
}